// Round 1
// baseline (598.838 us; speedup 1.0000x reference)
//
#include <hip/hip_runtime.h>
#include <hip/hip_bf16.h>
#include <math.h>

#define HID 128
#define DD 256        // 2*HID
#define NNODES 1023
#define NLEAVES 512

// ---------------- leaf gather: H[t] = embed[word_ids[t]] ----------------
__global__ void leaf_kernel(const float* __restrict__ embed,
                            const int* __restrict__ word_ids,
                            float* __restrict__ H) {
    const int t = blockIdx.x;            // 0..511 (leaves)
    const int h = threadIdx.x;           // 0..127
    H[(size_t)t * HID + h] = embed[(size_t)word_ids[t] * HID + h];
}

// ---------------- big levels (nn >= 32): one block per (node-tile, k) ----------------
// Block: 256 threads = 16 node-groups x 16 j-groups.
// q[n] = sum_j X[n,j] * ( W[j,k] + sum_i X[n,i] * V[k,i,j] );  H[n,k] = tanh(q + b[k])
template<int NT>
__global__ __launch_bounds__(256, 2)
void level_big(const float* __restrict__ V, const float* __restrict__ W,
               const float* __restrict__ b, const int* __restrict__ left,
               const int* __restrict__ right, float* __restrict__ H,
               int levelStart) {
    constexpr int NPT = NT / 16;            // nodes per thread
    static_assert(NPT >= 1, "NT>=16");
    __shared__ float XsT[DD * NT];          // [dim][node], transposed

    const int t = threadIdx.x;
    const int k = blockIdx.y;               // 0..127
    const int node0 = levelStart + blockIdx.x * NT;

    // ---- stage X transposed (lane-varies-node => conflict-free LDS writes) ----
    {
        const int n = t & (NT - 1);
        const int g = t / NT;               // 256/NT dim-groups
        const int node = node0 + n;
        const int lc = left[node], rc = right[node];
        const int d0 = g * NT;
        for (int dd = 0; dd < NT; ++dd) {
            const int d = d0 + dd;
            const int child = (d < HID) ? lc : rc;
            XsT[d * NT + n] = H[(size_t)child * HID + (d & (HID - 1))];
        }
    }
    __syncthreads();

    const int jg = t & 15;                  // j-group
    const int gg = t >> 4;                  // node-group 0..15
    const int n0 = gg * NPT;
    const float* __restrict__ Vk = V + (size_t)k * (DD * DD);

    float q[NPT];
#pragma unroll
    for (int a = 0; a < NPT; ++a) q[a] = 0.f;

#pragma unroll
    for (int jb = 0; jb < 4; ++jb) {
        const int j4 = jb * 64 + jg * 4;
        float y[NPT][4];
#pragma unroll
        for (int a = 0; a < NPT; ++a)
#pragma unroll
            for (int e = 0; e < 4; ++e) y[a][e] = 0.f;

        const float* vp = Vk + j4;
#pragma unroll 4
        for (int i = 0; i < DD; ++i) {
            const float4 v4 = *reinterpret_cast<const float4*>(vp + (size_t)i * DD);
            float xi[NPT];
#pragma unroll
            for (int a = 0; a < NPT; ++a) xi[a] = XsT[i * NT + n0 + a];
#pragma unroll
            for (int a = 0; a < NPT; ++a) {
                y[a][0] = fmaf(xi[a], v4.x, y[a][0]);
                y[a][1] = fmaf(xi[a], v4.y, y[a][1]);
                y[a][2] = fmaf(xi[a], v4.z, y[a][2]);
                y[a][3] = fmaf(xi[a], v4.w, y[a][3]);
            }
        }
        // W column contribution for this thread's j's (counted once per j)
        float w4[4];
#pragma unroll
        for (int e = 0; e < 4; ++e) w4[e] = W[(size_t)(j4 + e) * HID + k];
        // fold: q += X[n,j] * (y + W[j,k])
#pragma unroll
        for (int e = 0; e < 4; ++e) {
#pragma unroll
            for (int a = 0; a < NPT; ++a) {
                const float xv = XsT[(j4 + e) * NT + n0 + a];
                q[a] = fmaf(xv, y[a][e] + w4[e], q[a]);
            }
        }
    }

    // reduce across the 16 j-groups (lanes within each 16-lane group)
#pragma unroll
    for (int a = 0; a < NPT; ++a) {
#pragma unroll
        for (int m = 1; m < 16; m <<= 1)
            q[a] += __shfl_xor(q[a], m, 64);
    }
    if (jg == 0) {
        const float bk = b[k];
#pragma unroll
        for (int a = 0; a < NPT; ++a)
            H[(size_t)(node0 + n0 + a) * HID + k] = tanhf(q[a] + bk);
    }
}

// ---------------- small levels (nn <= 16): one block per k, all nodes ----------------
template<int NN>
__global__ __launch_bounds__(256, 2)
void level_small(const float* __restrict__ V, const float* __restrict__ W,
                 const float* __restrict__ b, const int* __restrict__ left,
                 const int* __restrict__ right, float* __restrict__ H,
                 int levelStart) {
    __shared__ float Xs[NN * DD];           // [node][dim]
    __shared__ float qred[NN * 17];

    const int t = threadIdx.x;
    const int k = blockIdx.x;               // 0..127

    for (int idx = t; idx < NN * DD; idx += 256) {
        const int n = idx >> 8, d = idx & 255;
        const int node = levelStart + n;
        const int child = (d < HID) ? left[node] : right[node];
        Xs[idx] = H[(size_t)child * HID + (d & (HID - 1))];
    }
    __syncthreads();

    const int jj = t & 15;                  // j-group
    const int ig = t >> 4;                  // i-block 0..15
    const float* __restrict__ Vk = V + (size_t)k * (DD * DD);

    float acc[NN];
#pragma unroll
    for (int n = 0; n < NN; ++n) acc[n] = 0.f;

#pragma unroll
    for (int jb = 0; jb < 4; ++jb) {
        const int j4 = jb * 64 + jj * 4;
        float4 xr[NN];
#pragma unroll
        for (int n = 0; n < NN; ++n)
            xr[n] = *reinterpret_cast<const float4*>(&Xs[n * DD + j4]);

        if (ig == 0) {                      // xW folded in exactly once per j
            float w4[4];
#pragma unroll
            for (int e = 0; e < 4; ++e) w4[e] = W[(size_t)(j4 + e) * HID + k];
#pragma unroll
            for (int n = 0; n < NN; ++n) {
                acc[n] = fmaf(xr[n].x, w4[0], acc[n]);
                acc[n] = fmaf(xr[n].y, w4[1], acc[n]);
                acc[n] = fmaf(xr[n].z, w4[2], acc[n]);
                acc[n] = fmaf(xr[n].w, w4[3], acc[n]);
            }
        }
#pragma unroll 4
        for (int r = 0; r < 16; ++r) {
            const int i = ig * 16 + r;
            const float4 v4 = *reinterpret_cast<const float4*>(Vk + (size_t)i * DD + j4);
#pragma unroll
            for (int n = 0; n < NN; ++n) {
                float d4;
                d4 = v4.x * xr[n].x;
                d4 = fmaf(v4.y, xr[n].y, d4);
                d4 = fmaf(v4.z, xr[n].z, d4);
                d4 = fmaf(v4.w, xr[n].w, d4);
                acc[n] = fmaf(Xs[n * DD + i], d4, acc[n]);
            }
        }
    }

#pragma unroll
    for (int n = 0; n < NN; ++n) {
#pragma unroll
        for (int m = 1; m < 16; m <<= 1)
            acc[n] += __shfl_xor(acc[n], m, 64);
    }
    if (jj == 0) {
#pragma unroll
        for (int n = 0; n < NN; ++n) qred[n * 17 + ig] = acc[n];
    }
    __syncthreads();
    if (t < NN) {
        float s = b[k];
#pragma unroll
        for (int ig2 = 0; ig2 < 16; ++ig2) s += qred[t * 17 + ig2];
        H[(size_t)(levelStart + t) * HID + k] = tanhf(s);
    }
}

// ---------------- logits + log_softmax ----------------
__global__ void out_kernel(const float* __restrict__ H,
                           const float* __restrict__ Wout,
                           const float* __restrict__ bout,
                           float* __restrict__ out) {
    const int t = blockIdx.x;               // node
    const int l = threadIdx.x;              // 0..63
    const float h0 = H[(size_t)t * HID + l];
    const float h1 = H[(size_t)t * HID + 64 + l];
    float p[5];
#pragma unroll
    for (int o = 0; o < 5; ++o) {
        p[o] = h0 * Wout[o * HID + l] + h1 * Wout[o * HID + 64 + l];
#pragma unroll
        for (int m = 1; m < 64; m <<= 1) p[o] += __shfl_xor(p[o], m, 64);
    }
    if (l == 0) {
        float lg[5], mx = -1e30f;
#pragma unroll
        for (int o = 0; o < 5; ++o) { lg[o] = p[o] + bout[o]; mx = fmaxf(mx, lg[o]); }
        float s = 0.f;
#pragma unroll
        for (int o = 0; o < 5; ++o) s += expf(lg[o] - mx);
        const float lse = mx + logf(s);
#pragma unroll
        for (int o = 0; o < 5; ++o) out[(size_t)t * 5 + o] = lg[o] - lse;
    }
}

extern "C" void kernel_launch(void* const* d_in, const int* in_sizes, int n_in,
                              void* d_out, int out_size, void* d_ws, size_t ws_size,
                              hipStream_t stream) {
    const float* embed   = (const float*)d_in[0];
    const float* V       = (const float*)d_in[1];
    const float* W       = (const float*)d_in[2];
    const float* b       = (const float*)d_in[3];
    const float* Woutw   = (const float*)d_in[4];
    const float* Woutb   = (const float*)d_in[5];
    const int*   wordids = (const int*)d_in[6];
    const int*   left    = (const int*)d_in[7];
    const int*   right   = (const int*)d_in[8];
    // d_in[9] (is_leaf, bool) unused: balanced tree => leaves are exactly t<512.

    float* H   = (float*)d_ws;              // 1023 x 128 fp32 state
    float* out = (float*)d_out;

    leaf_kernel<<<NLEAVES, HID, 0, stream>>>(embed, wordids, H);

    // levels: (start, nn) = (512,256)(768,128)(896,64)(960,32)(992,16)(1008,8)(1016,4)(1020,2)(1022,1)
    level_big<64><<<dim3(4, 128), 256, 0, stream>>>(V, W, b, left, right, H, 512);
    level_big<64><<<dim3(2, 128), 256, 0, stream>>>(V, W, b, left, right, H, 768);
    level_big<32><<<dim3(2, 128), 256, 0, stream>>>(V, W, b, left, right, H, 896);
    level_big<16><<<dim3(2, 128), 256, 0, stream>>>(V, W, b, left, right, H, 960);
    level_small<16><<<128, 256, 0, stream>>>(V, W, b, left, right, H, 992);
    level_small<8> <<<128, 256, 0, stream>>>(V, W, b, left, right, H, 1008);
    level_small<4> <<<128, 256, 0, stream>>>(V, W, b, left, right, H, 1016);
    level_small<2> <<<128, 256, 0, stream>>>(V, W, b, left, right, H, 1020);
    level_small<1> <<<128, 256, 0, stream>>>(V, W, b, left, right, H, 1022);

    out_kernel<<<NNODES, 64, 0, stream>>>(H, Woutw, Woutb, out);
}

// Round 4
// 311.486 us; speedup vs baseline: 1.9225x; 1.9225x over previous
//
#include <hip/hip_runtime.h>
#include <math.h>

#define HID 128
#define DD 256        // 2*HID
#define NNODES 1023
#define NLEAVES 512

typedef __attribute__((ext_vector_type(8))) short short8;   // 8 bf16 (4 VGPRs)
typedef __attribute__((ext_vector_type(4))) float f32x4;    // MFMA accumulator

__device__ __forceinline__ unsigned short f2bf(float f) {   // fp32 -> bf16 RNE
    unsigned int u = __float_as_uint(f);
    u += 0x7FFFu + ((u >> 16) & 1u);
    return (unsigned short)(u >> 16);
}
__device__ __forceinline__ float bf2f(unsigned short s) {
    return __uint_as_float(((unsigned int)s) << 16);
}
// pack two floats into hi-pair and lo-pair bf16 words (x ~= hi + lo, ~17 mantissa bits)
__device__ __forceinline__ void pack_hilo(float a, float c, unsigned& h, unsigned& l) {
    const unsigned short ha = f2bf(a), hc = f2bf(c);
    const unsigned short la = f2bf(a - bf2f(ha)), lc = f2bf(c - bf2f(hc));
    h = (unsigned)ha | ((unsigned)hc << 16);
    l = (unsigned)la | ((unsigned)lc << 16);
}

// ---------------- V fp32 -> bf16 hi/lo (layout preserved: [k][i][j], j contiguous) ----
__global__ void conv_kernel(const float* __restrict__ V,
                            unsigned short* __restrict__ Vh,
                            unsigned short* __restrict__ Vl) {
    const size_t t = (size_t)blockIdx.x * 256 + threadIdx.x;  // 8 floats per thread
    const float4 a = ((const float4*)V)[2 * t];
    const float4 c = ((const float4*)V)[2 * t + 1];
    uint4 ph, pl;
    pack_hilo(a.x, a.y, ph.x, pl.x);
    pack_hilo(a.z, a.w, ph.y, pl.y);
    pack_hilo(c.x, c.y, ph.z, pl.z);
    pack_hilo(c.z, c.w, ph.w, pl.w);
    ((uint4*)Vh)[t] = ph;
    ((uint4*)Vl)[t] = pl;
}

// ---------------- leaf gather: H[t] = embed[word_ids[t]] ----------------
__global__ void leaf_kernel(const float* __restrict__ embed,
                            const int* __restrict__ word_ids,
                            float* __restrict__ H) {
    const int t = blockIdx.x;
    const int h = threadIdx.x;
    H[(size_t)t * HID + h] = embed[(size_t)word_ids[t] * HID + h];
}

// ---------------- MFMA level kernel (double-bf16) ----------------
// Block = (MT*16-node tile, k). Z[n,i] = sum_j X[n,j] V[k,i,j] via 3 MFMA terms
// (XhVh + XlVh + XhVl); q[n] = sum_i X[n,i]*(Z[n,i]+W[i,k]); H[n,k]=tanh(q+b[k]).
template<int MT, int GX>
__global__ __launch_bounds__(256)
void level_mfma(const unsigned short* __restrict__ Vh, const unsigned short* __restrict__ Vl,
                const float* __restrict__ W, const float* __restrict__ b,
                const int* __restrict__ left, const int* __restrict__ right,
                float* __restrict__ H, int levelStart, int nn) {
    constexpr int ROWS = MT * 16;
    __shared__ __align__(16) unsigned short Xh[ROWS * 256];  // XOR-swizzled bf16 hi
    __shared__ __align__(16) unsigned short Xl[ROWS * 256];  // bf16 lo
    __shared__ float qred[ROWS * 4];

    const int t = threadIdx.x;
    // bijective XCD swizzle: k-chunk (k/16) -> fixed XCD, consistent across levels
    const int orig = blockIdx.x + GX * blockIdx.y;
    const int vid = (orig & 7) * ((GX * 128) >> 3) + (orig >> 3);
    const int k = vid / GX;
    const int n0 = (vid % GX) * ROWS;

    // ---- stage X = concat(H[left], H[right]) as hi/lo bf16, swizzle ^((row&7)<<3) ----
    for (int idx = t; idx < ROWS * 32; idx += 256) {
        const int row = idx >> 5;
        const int i0 = (idx & 31) * 8;
        const int n = n0 + row;
        uint4 ph = make_uint4(0u, 0u, 0u, 0u), pl = ph;
        if (n < nn) {
            const int node = levelStart + n;
            const int child = (i0 < HID) ? left[node] : right[node];
            const float4* hp = (const float4*)&H[(size_t)child * HID + (i0 & 127)];
            const float4 x0 = hp[0], x1 = hp[1];
            pack_hilo(x0.x, x0.y, ph.x, pl.x);
            pack_hilo(x0.z, x0.w, ph.y, pl.y);
            pack_hilo(x1.x, x1.y, ph.z, pl.z);
            pack_hilo(x1.z, x1.w, ph.w, pl.w);
        }
        const int ad = (row * 256 + i0) ^ ((row & 7) << 3);
        *(uint4*)&Xh[ad] = ph;
        *(uint4*)&Xl[ad] = pl;
    }
    __syncthreads();

    const int w = t >> 6;              // wave -> i-range [w*64, w*64+64)
    const int lane = t & 63;
    const int colsel = lane & 15;
    const int kg = lane >> 4;
    const int ibase = w * 64;

    f32x4 acc[MT][4];
#pragma unroll
    for (int m = 0; m < MT; ++m)
#pragma unroll
        for (int it = 0; it < 4; ++it) acc[m][it] = (f32x4){0.f, 0.f, 0.f, 0.f};

    const size_t vkb = ((size_t)k << 16);

#pragma unroll
    for (int ks = 0; ks < 8; ++ks) {           // K = j, 8 steps of 32
        const int jb = ks * 32 + kg * 8;
        short8 ah[MT], al[MT];
#pragma unroll
        for (int m = 0; m < MT; ++m) {
            const int row = m * 16 + colsel;
            const int ad = (row * 256 + jb) ^ ((row & 7) << 3);
            ah[m] = *(const short8*)&Xh[ad];
            al[m] = *(const short8*)&Xl[ad];
        }
#pragma unroll
        for (int it = 0; it < 4; ++it) {
            const int icol = ibase + it * 16 + colsel;
            const size_t vo = vkb + (size_t)icol * 256 + jb;
            const short8 bh = *(const short8*)&Vh[vo];
            const short8 bl = *(const short8*)&Vl[vo];
#pragma unroll
            for (int m = 0; m < MT; ++m)
                acc[m][it] = __builtin_amdgcn_mfma_f32_16x16x32_bf16(ah[m], bh, acc[m][it], 0, 0, 0);
#pragma unroll
            for (int m = 0; m < MT; ++m)
                acc[m][it] = __builtin_amdgcn_mfma_f32_16x16x32_bf16(al[m], bh, acc[m][it], 0, 0, 0);
#pragma unroll
            for (int m = 0; m < MT; ++m)
                acc[m][it] = __builtin_amdgcn_mfma_f32_16x16x32_bf16(ah[m], bl, acc[m][it], 0, 0, 0);
        }
    }

    // ---- epilogue: q[n] += X[n,i]*(Z[n,i]+W[i,k]); C layout col=lane&15, row=(lane>>4)*4+r
    float q[MT][4];
#pragma unroll
    for (int m = 0; m < MT; ++m)
#pragma unroll
        for (int r = 0; r < 4; ++r) q[m][r] = 0.f;

#pragma unroll
    for (int it = 0; it < 4; ++it) {
        const int ig = ibase + it * 16 + colsel;
        const float wv = W[(size_t)ig * HID + k];
#pragma unroll
        for (int m = 0; m < MT; ++m) {
#pragma unroll
            for (int r = 0; r < 4; ++r) {
                const int row = m * 16 + kg * 4 + r;
                const int ad = (row * 256 + ig) ^ ((row & 7) << 3);
                const float xv = bf2f(Xh[ad]) + bf2f(Xl[ad]);
                q[m][r] = fmaf(xv, acc[m][it][r] + wv, q[m][r]);
            }
        }
    }
#pragma unroll
    for (int m = 0; m < MT; ++m)
#pragma unroll
        for (int r = 0; r < 4; ++r)
#pragma unroll
            for (int msk = 1; msk < 16; msk <<= 1)
                q[m][r] += __shfl_xor(q[m][r], msk, 64);

    if (colsel == 0) {
#pragma unroll
        for (int m = 0; m < MT; ++m)
#pragma unroll
            for (int r = 0; r < 4; ++r)
                qred[(m * 16 + kg * 4 + r) * 4 + w] = q[m][r];
    }
    __syncthreads();
    if (t < ROWS) {
        const int n = n0 + t;
        if (n < nn) {
            const float s = b[k] + qred[t * 4 + 0] + qred[t * 4 + 1]
                                 + qred[t * 4 + 2] + qred[t * 4 + 3];
            H[(size_t)(levelStart + n) * HID + k] = tanhf(s);
        }
    }
}

// ---------------- logits + log_softmax ----------------
__global__ void out_kernel(const float* __restrict__ H,
                           const float* __restrict__ Wout,
                           const float* __restrict__ bout,
                           float* __restrict__ out) {
    const int t = blockIdx.x;
    const int l = threadIdx.x;
    const float h0 = H[(size_t)t * HID + l];
    const float h1 = H[(size_t)t * HID + 64 + l];
    float p[5];
#pragma unroll
    for (int o = 0; o < 5; ++o) {
        p[o] = h0 * Wout[o * HID + l] + h1 * Wout[o * HID + 64 + l];
#pragma unroll
        for (int m = 1; m < 64; m <<= 1) p[o] += __shfl_xor(p[o], m, 64);
    }
    if (l == 0) {
        float lg[5], mx = -1e30f;
#pragma unroll
        for (int o = 0; o < 5; ++o) { lg[o] = p[o] + bout[o]; mx = fmaxf(mx, lg[o]); }
        float s = 0.f;
#pragma unroll
        for (int o = 0; o < 5; ++o) s += expf(lg[o] - mx);
        const float lse = mx + logf(s);
#pragma unroll
        for (int o = 0; o < 5; ++o) out[(size_t)t * 5 + o] = lg[o] - lse;
    }
}

extern "C" void kernel_launch(void* const* d_in, const int* in_sizes, int n_in,
                              void* d_out, int out_size, void* d_ws, size_t ws_size,
                              hipStream_t stream) {
    const float* embed   = (const float*)d_in[0];
    const float* V       = (const float*)d_in[1];
    const float* W       = (const float*)d_in[2];
    const float* b       = (const float*)d_in[3];
    const float* Woutw   = (const float*)d_in[4];
    const float* Woutb   = (const float*)d_in[5];
    const int*   wordids = (const int*)d_in[6];
    const int*   left    = (const int*)d_in[7];
    const int*   right   = (const int*)d_in[8];
    // d_in[9] (is_leaf) unused: balanced tree => leaves are exactly t<512.

    const size_t VSZ = (size_t)128 * 256 * 256;               // 8.39M elems
    unsigned short* Vbh = (unsigned short*)d_ws;              // 16.78 MB
    unsigned short* Vbl = Vbh + VSZ;                          // 16.78 MB
    float* H   = (float*)((char*)d_ws + 4 * VSZ);             // 1023x128 fp32
    float* out = (float*)d_out;

    conv_kernel<<<4096, 256, 0, stream>>>(V, Vbh, Vbl);
    leaf_kernel<<<NLEAVES, HID, 0, stream>>>(embed, wordids, H);

    // levels: (start,nn): (512,256)(768,128)(896,64)(960,32)(992,16)(1008,8)(1016,4)(1020,2)(1022,1)
    level_mfma<4,4><<<dim3(4,128), 256, 0, stream>>>(Vbh, Vbl, W, b, left, right, H, 512, 256);
    level_mfma<4,2><<<dim3(2,128), 256, 0, stream>>>(Vbh, Vbl, W, b, left, right, H, 768, 128);
    level_mfma<4,1><<<dim3(1,128), 256, 0, stream>>>(Vbh, Vbl, W, b, left, right, H, 896,  64);
    level_mfma<2,1><<<dim3(1,128), 256, 0, stream>>>(Vbh, Vbl, W, b, left, right, H, 960,  32);
    level_mfma<1,1><<<dim3(1,128), 256, 0, stream>>>(Vbh, Vbl, W, b, left, right, H, 992,  16);
    level_mfma<1,1><<<dim3(1,128), 256, 0, stream>>>(Vbh, Vbl, W, b, left, right, H, 1008,  8);
    level_mfma<1,1><<<dim3(1,128), 256, 0, stream>>>(Vbh, Vbl, W, b, left, right, H, 1016,  4);
    level_mfma<1,1><<<dim3(1,128), 256, 0, stream>>>(Vbh, Vbl, W, b, left, right, H, 1020,  2);
    level_mfma<1,1><<<dim3(1,128), 256, 0, stream>>>(Vbh, Vbl, W, b, left, right, H, 1022,  1);

    out_kernel<<<NNODES, 64, 0, stream>>>(H, Woutw, Woutb, out);
}